// Round 4
// baseline (3302.689 us; speedup 1.0000x reference)
//
#include <hip/hip_runtime.h>
#include <stdint.h>

// Farthest-point sampling (N=100000, M=1024) + feat/coord gather.
// Latency-bound: 1023 sequential argmax steps. Barrier-free design:
// 128 blocks x 64 threads (one wave each). Per iteration each wave does a
// register distance-update, a two-phase DPP argmax (no LDS, no bpermute),
// publishes one tagged 64-bit key to its slot, then all lanes poll the 128
// slots (2 per lane) and redundantly DPP-reduce them -> every wave derives
// the same winner. Relaxed agent-scope atomics: payload fits one u64,
// parity double-buffer + monotonic tag make stale reads impossible.
// Safety valves (never hit in normal operation): bounded spin + index clamps
// so any failure degrades to a wrong answer, not a hung container.

#define N_PTS   100000
#define M_SEL   1024
#define NBLK    128
#define NTHR    64
#define TOT     (NBLK * NTHR)                 // 8192 threads
#define PPT     13                            // ceil(100000/8192)
#define REMTH   (N_PTS - (PPT - 1) * TOT)     // 1696: threads g<1696 own a 13th point
#define NSLOT   128

typedef unsigned long long u64;
typedef unsigned int u32;

__device__ __forceinline__ u32 umax32(u32 a, u32 b) { return a > b ? a : b; }

// One DPP max step: v = max(v, dpp_move(v)). Invalid source lanes contribute
// identity 0 (old=0, bound_ctrl=false). All operands non-negative here.
template <int CTRL>
__device__ __forceinline__ u32 dpp_max_step(u32 v) {
    u32 t = (u32)__builtin_amdgcn_update_dpp(0, (int)v, CTRL, 0xF, 0xF, false);
    return umax32(v, t);
}

// Full wave64 u32 max; returns the max broadcast uniformly (SGPR via readlane).
__device__ __forceinline__ u32 wave_umax(u32 v) {
    v = dpp_max_step<0x111>(v);  // row_shr:1
    v = dpp_max_step<0x112>(v);  // row_shr:2
    v = dpp_max_step<0x114>(v);  // row_shr:4
    v = dpp_max_step<0x118>(v);  // row_shr:8  -> lanes 15/31/47/63 = row maxes
    v = dpp_max_step<0x142>(v);  // row_bcast:15
    v = dpp_max_step<0x143>(v);  // row_bcast:31 -> lane 63 = wave max
    return (u32)__builtin_amdgcn_readlane((int)v, 63);
}

// Zero the 2*NSLOT handshake slots (d_ws is poisoned 0xAA before every launch)
// and emit idx[0] = 0 (reference starts from index 0).
__global__ __launch_bounds__(256) void fps_init(u64* slots, int* idx_out) {
    int i = threadIdx.x;
    slots[i] = 0ull;
    if (i == 0) idx_out[0] = 0;
}

__global__ __launch_bounds__(NTHR) void fps_kernel(const float* __restrict__ coord,
                                                   u64* __restrict__ slots,
                                                   int* __restrict__ idx_out) {
    const int tid = threadIdx.x;   // 0..63 (lane id)
    const int bid = blockIdx.x;    // 0..127 (publisher id)
    const int g   = bid * NTHR + tid;

    // Per-thread point state, fully in registers.
    float px[PPT], py[PPT], pz[PPT], dmin[PPT];
#pragma unroll
    for (int t = 0; t < PPT; ++t) {
        const bool ok = (t < PPT - 1) || (g < REMTH);
        const int  p  = ok ? (g + t * TOT) : 0;
        px[t]  = coord[3 * p + 0];
        py[t]  = coord[3 * p + 1];
        pz[t]  = coord[3 * p + 2];
        dmin[t] = 1e10f;  // matches jnp.full((N,), 1e10)
    }

    int fid = 0;  // reference fixes the start index at 0
    for (int it = 1; it < M_SEL; ++it) {
        // Centroid (uniform address -> scalar loads, L2-resident).
        const float cx = coord[3 * fid + 0];
        const float cy = coord[3 * fid + 1];
        const float cz = coord[3 * fid + 2];

        // Update running min distances; per-thread best as packed key:
        // dist_bits(32) << 17 | (131071 - idx). Larger dist wins; equal dist
        // -> smaller idx (jnp.argmax first-max semantics; within a thread the
        // first/lowest-p occurrence is kept because equal keys don't replace).
        // Distance math mirrors XLA: separate mul/add roundings (no FMA).
        u64 best = 0;
#pragma unroll
        for (int t = 0; t < PPT; ++t) {
            const float dx = px[t] - cx;
            const float dy = py[t] - cy;
            const float dz = pz[t] - cz;
            const float d  = __fadd_rn(__fadd_rn(__fmul_rn(dx, dx), __fmul_rn(dy, dy)),
                                       __fmul_rn(dz, dz));
            const float nd = fminf(dmin[t], d);
            dmin[t] = nd;
            const bool ok = (t < PPT - 1) || (g < REMTH);
            if (ok) {
                const int p   = g + t * TOT;
                const u64 key = ((u64)__float_as_uint(nd) << 17) | (u64)(131071 - p);
                if (key > best) best = key;
            }
        }

        // Wave argmax, two-phase DPP (dist bits are IEEE f32 of non-negative
        // values -> unsigned compare is order-preserving).
        const u32 dbits  = (u32)(best >> 17);
        const u32 maxd   = wave_umax(dbits);
        const u32 inv    = (dbits == maxd) ? (u32)(best & 0x1FFFF) : 0u;
        const u32 maxinv = wave_umax(inv);  // max inverted idx = min idx among tied

        // Publish tagged key. Parity double-buffer + monotonic tag: a slot,
        // once tagged for `it`, is stable until this wave itself advances
        // (overwrite needs it+2, which needs everyone past it+1).
        u64* base = slots + (size_t)(it & 1) * NSLOT;
        if (tid == 0) {
            const u64 tagged = ((u64)it << 49) | ((u64)maxd << 17) | (u64)maxinv;
            __hip_atomic_store(&base[bid], tagged, __ATOMIC_RELAXED,
                               __HIP_MEMORY_SCOPE_AGENT);
        }

        // Poll: lane L watches slots L and L+64. Both loads issue every round
        // (independent -> pipelined); reloading a matched slot is safe.
        // Bounded spin: normal wait is <10 rounds; the bound only exists so
        // an unforeseen failure can't hang the container.
        u64* sa = &base[tid];
        u64* sb = &base[tid + 64];
        u64 a = 0, b = 0;
        for (int spin = 0; spin < (1 << 24); ++spin) {
            a = __hip_atomic_load(sa, __ATOMIC_RELAXED, __HIP_MEMORY_SCOPE_AGENT);
            b = __hip_atomic_load(sb, __ATOMIC_RELAXED, __HIP_MEMORY_SCOPE_AGENT);
            if (((int)(a >> 49) == it) & ((int)(b >> 49) == it)) break;
        }

        // Redundant global reduce: tags equal -> max over tagged == max over key.
        const u64 w       = a > b ? a : b;
        const u32 wd      = (u32)(w >> 17);          // truncation strips the tag
        const u32 gmaxd   = wave_umax(wd);
        const u32 ginv    = (wd == gmaxd) ? (u32)(w & 0x1FFFF) : 0u;
        const u32 gmaxinv = wave_umax(ginv);
        fid = 131071 - (int)gmaxinv;
        if (fid < 0) fid = 0;                        // safety clamp (unreachable
        if (fid >= N_PTS) fid = N_PTS - 1;           //  in correct operation)

        if (bid == 0 && tid == 0) idx_out[it] = fid;  // fire-and-forget
    }
}

// out[0 .. 524287]        = feat[idx]  (1024 x 512)
// out[524288 .. 527359]   = coord[idx] (1024 x 3)
__global__ __launch_bounds__(128) void gather_kernel(const float* __restrict__ feat,
                                                     const float* __restrict__ coord,
                                                     const int* __restrict__ idx,
                                                     float* __restrict__ out) {
    const int m = blockIdx.x;
    int f = idx[m];
    if (f < 0) f = 0;
    if (f >= N_PTS) f = N_PTS - 1;                   // safety clamp
    const int t = threadIdx.x;
    const float4* src = (const float4*)(feat + (size_t)f * 512);
    float4*       dst = (float4*)(out + (size_t)m * 512);
    dst[t] = src[t];  // 128 threads x float4 = 512 floats
    if (t < 3) out[(size_t)M_SEL * 512 + m * 3 + t] = coord[f * 3 + t];
}

extern "C" void kernel_launch(void* const* d_in, const int* in_sizes, int n_in,
                              void* d_out, int out_size, void* d_ws, size_t ws_size,
                              hipStream_t stream) {
    const float* feat  = (const float*)d_in[0];   // (100000, 512) f32
    const float* coord = (const float*)d_in[1];   // (100000, 3)   f32
    float* out = (float*)d_out;

    // ws layout: [0,2048) handshake slots (2*NSLOT u64); [2048,6144) idx int32[1024]
    u64* slots = (u64*)d_ws;
    int* idx   = (int*)((char*)d_ws + 2048);

    fps_init<<<1, 256, 0, stream>>>(slots, idx);
    fps_kernel<<<NBLK, NTHR, 0, stream>>>(coord, slots, idx);
    gather_kernel<<<M_SEL, 128, 0, stream>>>(feat, coord, idx, out);
}

// Round 5
// 3100.508 us; speedup vs baseline: 1.0652x; 1.0652x over previous
//
#include <hip/hip_runtime.h>
#include <stdint.h>

// Farthest-point sampling (N=100000, M=1024) + feat/coord gather.
// Latency-bound: 1023 sequential global argmax steps. Structure (passing R4):
// 128 fps blocks (1 wave each) publish tagged 64-bit keys to parity
// double-buffered slots (relaxed agent atomics, self-validating tags), poll
// all 128 slots, and redundantly DPP-reduce -> every wave derives the winner.
// NEW this round:
//  - 96 "clock-warming" blocks of dense FMA work (DVFS A/B test): the kernel
//    is ~2% utilized, so sclk parks at idle and inflates the serial VALU work
//    4-5x. Busy blocks exit when the leader sets a done-flag.
//  - Slimmed update loop: float-compare argmax, key packed once after loop.
//  - fps waves run at s_setprio(2) in case a busy block shares their CU.

#define N_PTS   100000
#define M_SEL   1024
#define NBLK    128                            // fps publisher blocks
#define NBUSY   96                             // clock-warming blocks
#define NTHR_A  64                             // active fps threads (1 wave)
#define TOT     (NBLK * NTHR_A)                // 8192 threads
#define PPT     13                             // ceil(100000/8192)
#define REMTH   (N_PTS - (PPT - 1) * TOT)      // 1696
#define NSLOT   128

typedef unsigned long long u64;
typedef unsigned int u32;

__device__ __forceinline__ u32 umax32(u32 a, u32 b) { return a > b ? a : b; }

// One DPP max step: v = max(v, dpp_move(v)). old=0, bound_ctrl=false ->
// invalid source lanes contribute identity 0 (all operands non-negative).
template <int CTRL>
__device__ __forceinline__ u32 dpp_max_step(u32 v) {
    u32 t = (u32)__builtin_amdgcn_update_dpp(0, (int)v, CTRL, 0xF, 0xF, false);
    return umax32(v, t);
}

// Full wave64 u32 max, broadcast uniformly via readlane.
__device__ __forceinline__ u32 wave_umax(u32 v) {
    v = dpp_max_step<0x111>(v);  // row_shr:1
    v = dpp_max_step<0x112>(v);  // row_shr:2
    v = dpp_max_step<0x114>(v);  // row_shr:4
    v = dpp_max_step<0x118>(v);  // row_shr:8
    v = dpp_max_step<0x142>(v);  // row_bcast:15
    v = dpp_max_step<0x143>(v);  // row_bcast:31 -> lane 63 = wave max
    return (u32)__builtin_amdgcn_readlane((int)v, 63);
}

// Zero handshake slots + done-flag (d_ws is re-poisoned 0xAA before every
// timed launch) and emit idx[0] = 0 (reference starts from index 0).
__global__ __launch_bounds__(256) void fps_init(u64* slots, int* idx_out, u32* flag) {
    int i = threadIdx.x;
    slots[i] = 0ull;                 // 2*NSLOT = 256 slots
    if (i == 0) { idx_out[0] = 0; flag[0] = 0u; }
}

__global__ __launch_bounds__(256) void fps_kernel(const float* __restrict__ coord,
                                                  u64* __restrict__ slots,
                                                  int* __restrict__ idx_out,
                                                  u32* __restrict__ flag) {
    const int bid = blockIdx.x;

    if (bid >= NBLK) {
        // ---- clock-warming role: dense independent FMA chains, exit on flag.
        float a0 = (float)threadIdx.x * 1e-3f + 1.0f;
        float a1 = a0 + 0.11f, a2 = a0 + 0.22f, a3 = a0 + 0.33f;
        float a4 = a0 + 0.44f, a5 = a0 + 0.55f, a6 = a0 + 0.66f, a7 = a0 + 0.77f;
        const float m = 1.0000002f, c = 1e-9f;
        for (int o = 0; o < (1 << 17); ++o) {          // bounded (safety)
            for (int j = 0; j < 8; ++j) {
#pragma unroll
                for (int k = 0; k < 64; ++k) {         // 8x64x8 = 4096 FMA/check
                    a0 = __fmaf_rn(a0, m, c); a1 = __fmaf_rn(a1, m, c);
                    a2 = __fmaf_rn(a2, m, c); a3 = __fmaf_rn(a3, m, c);
                    a4 = __fmaf_rn(a4, m, c); a5 = __fmaf_rn(a5, m, c);
                    a6 = __fmaf_rn(a6, m, c); a7 = __fmaf_rn(a7, m, c);
                }
            }
            if (__hip_atomic_load(flag, __ATOMIC_RELAXED, __HIP_MEMORY_SCOPE_AGENT))
                break;
        }
        // Keep the FMA chains alive (condition is never true in practice;
        // flag[1] is an unused scratch word).
        float s = a0 + a1 + a2 + a3 + a4 + a5 + a6 + a7;
        if (__float_as_uint(s) == 0xDEADBEEFu && threadIdx.x == 0)
            flag[1] = __float_as_uint(s);
        return;
    }

    if (threadIdx.x >= NTHR_A) return;   // fps blocks use wave 0 only; no barriers
    __builtin_amdgcn_s_setprio(2);       // win issue arbitration if CU is shared

    const int tid = threadIdx.x;         // 0..63
    const int g   = bid * NTHR_A + tid;

    // Per-thread point state, fully in registers.
    float px[PPT], py[PPT], pz[PPT], dmin[PPT];
#pragma unroll
    for (int t = 0; t < PPT; ++t) {
        const bool ok = (t < PPT - 1) || (g < REMTH);
        const int  p  = ok ? (g + t * TOT) : 0;
        px[t]  = coord[3 * p + 0];
        py[t]  = coord[3 * p + 1];
        pz[t]  = coord[3 * p + 2];
        dmin[t] = 1e10f;  // matches jnp.full((N,), 1e10)
    }

    int fid = 0;  // reference fixes the start index at 0
    for (int it = 1; it < M_SEL; ++it) {
        const float cx = coord[3 * fid + 0];
        const float cy = coord[3 * fid + 1];
        const float cz = coord[3 * fid + 2];

        // Update running min distances; thread-local argmax via float compare.
        // Strict > over ascending p keeps the smallest p among equal dists ==
        // jnp.argmax first-max semantics (identical to R4's per-point key max).
        // Distance math mirrors XLA: separate mul/add roundings (no FMA).
        float best_d = -1.0f;
        int   best_p = 0;
#pragma unroll
        for (int t = 0; t < PPT; ++t) {
            const float dx = px[t] - cx;
            const float dy = py[t] - cy;
            const float dz = pz[t] - cz;
            const float d  = __fadd_rn(__fadd_rn(__fmul_rn(dx, dx), __fmul_rn(dy, dy)),
                                       __fmul_rn(dz, dz));
            const float nd = fminf(dmin[t], d);
            dmin[t] = nd;
            const bool ok = (t < PPT - 1) || (g < REMTH);
            if (ok && (nd > best_d)) { best_d = nd; best_p = g + t * TOT; }
        }

        // Wave argmax, two-phase DPP (non-negative f32 bits: unsigned compare
        // is order-preserving).
        const u32 dbits  = __float_as_uint(best_d);
        const u32 maxd   = wave_umax(dbits);
        const u32 inv    = (dbits == maxd) ? (u32)(131071 - best_p) : 0u;
        const u32 maxinv = wave_umax(inv);  // max inverted idx = min idx among tied

        // Publish tagged key. Parity double-buffer + monotonic tag: a slot
        // tagged `it` is stable until every wave has passed `it+1`.
        u64* base = slots + (size_t)(it & 1) * NSLOT;
        if (tid == 0) {
            const u64 tagged = ((u64)it << 49) | ((u64)maxd << 17) | (u64)maxinv;
            __hip_atomic_store(&base[bid], tagged, __ATOMIC_RELAXED,
                               __HIP_MEMORY_SCOPE_AGENT);
        }

        // Poll: lane L watches slots L and L+64 (independent, pipelined loads).
        // Bounded spin: normal wait is a few rounds; bound only prevents a
        // hung container on unforeseen failure.
        u64* sa = &base[tid];
        u64* sb = &base[tid + 64];
        u64 a = 0, b = 0;
        for (int spin = 0; spin < (1 << 24); ++spin) {
            a = __hip_atomic_load(sa, __ATOMIC_RELAXED, __HIP_MEMORY_SCOPE_AGENT);
            b = __hip_atomic_load(sb, __ATOMIC_RELAXED, __HIP_MEMORY_SCOPE_AGENT);
            if (((int)(a >> 49) == it) & ((int)(b >> 49) == it)) break;
        }

        // Redundant global reduce (tags equal -> u64 compare == key compare).
        const u64 w       = a > b ? a : b;
        const u32 wd      = (u32)(w >> 17);           // strips the tag
        const u32 gmaxd   = wave_umax(wd);
        const u32 ginv    = (wd == gmaxd) ? (u32)(w & 0x1FFFF) : 0u;
        const u32 gmaxinv = wave_umax(ginv);
        fid = 131071 - (int)gmaxinv;
        if (fid < 0) fid = 0;                         // safety clamps
        if (fid >= N_PTS) fid = N_PTS - 1;            //  (unreachable normally)

        if (bid == 0 && tid == 0) idx_out[it] = fid;  // fire-and-forget
    }

    if (bid == 0 && tid == 0)                         // release the warmers
        __hip_atomic_store(flag, 1u, __ATOMIC_RELAXED, __HIP_MEMORY_SCOPE_AGENT);
}

// out[0 .. 524287]      = feat[idx]  (1024 x 512)
// out[524288 .. 527359] = coord[idx] (1024 x 3)
__global__ __launch_bounds__(128) void gather_kernel(const float* __restrict__ feat,
                                                     const float* __restrict__ coord,
                                                     const int* __restrict__ idx,
                                                     float* __restrict__ out) {
    const int m = blockIdx.x;
    int f = idx[m];
    if (f < 0) f = 0;
    if (f >= N_PTS) f = N_PTS - 1;                    // safety clamp
    const int t = threadIdx.x;
    const float4* src = (const float4*)(feat + (size_t)f * 512);
    float4*       dst = (float4*)(out + (size_t)m * 512);
    dst[t] = src[t];  // 128 threads x float4 = 512 floats
    if (t < 3) out[(size_t)M_SEL * 512 + m * 3 + t] = coord[f * 3 + t];
}

extern "C" void kernel_launch(void* const* d_in, const int* in_sizes, int n_in,
                              void* d_out, int out_size, void* d_ws, size_t ws_size,
                              hipStream_t stream) {
    const float* feat  = (const float*)d_in[0];   // (100000, 512) f32
    const float* coord = (const float*)d_in[1];   // (100000, 3)   f32
    float* out = (float*)d_out;

    // ws layout: [0,2048) slots (2*NSLOT u64); [2048,6144) idx int32[1024];
    //            [6144,6152) done-flag (2 u32)
    u64* slots = (u64*)d_ws;
    int* idx   = (int*)((char*)d_ws + 2048);
    u32* flag  = (u32*)((char*)d_ws + 6144);

    fps_init<<<1, 256, 0, stream>>>(slots, idx, flag);
    fps_kernel<<<NBLK + NBUSY, 256, 0, stream>>>(coord, slots, idx, flag);
    gather_kernel<<<M_SEL, 128, 0, stream>>>(feat, coord, idx, out);
}

// Round 6
// 1444.793 us; speedup vs baseline: 2.2859x; 2.1460x over previous
//
#include <hip/hip_runtime.h>
#include <stdint.h>

// Farthest-point sampling (N=100000, M=1024) + feat/coord gather.
// R5 established: cross-XCD sync RTT ~2.5us is intrinsic (structure- and
// clock-insensitive). This round: EXACT batched candidate-pool FPS to cut
// the number of global syncs from 1023 to ~#refills.
//
// Per refill: each of 128 waves publishes its top-8 points by current dmin
// plus its 9th-best value; T = max of 9th-bests bounds every non-pool
// point's dmin (dmin only decreases). All waves load the 1024-entry pool
// (dmin+coords in registers, 16/lane) and redundantly, deterministically
// run FPS inside the pool with ZERO communication while pool-max > T
// strictly. Ties / exhaustion -> resync; a batch with zero progress falls
// back to one exact R4-style global argmax step (guaranteed progress).
// jnp.argmax tie-break (max dist, min index) preserved via key packing
// (dist<<17 | 131071-idx) at every level; strict >T is exactly the
// boundary where an outside point could win a tie.
// All spins bounded; all indices clamped: failures degrade to wrong
// answers, never hangs/faults.

#define N_PTS   100000
#define M_SEL   1024
#define NBLK    128
#define NTHR    64
#define TOT     (NBLK * NTHR)                 // 8192 threads
#define PPT     13                            // ceil(100000/8192)
#define REMTH   (N_PTS - (PPT - 1) * TOT)     // 1696
#define KPW     8                             // pool candidates per wave
#define CPOOL   (NBLK * KPW)                  // 1024 pool entries
#define SPL     (CPOOL / 64)                  // 16 pool slots per lane
#define SPIN_MAX (1 << 20)

typedef unsigned long long u64;
typedef unsigned int u32;

__device__ __forceinline__ u32 umax32(u32 a, u32 b) { return a > b ? a : b; }

template <int CTRL>
__device__ __forceinline__ u32 dpp_max_step(u32 v) {
    u32 t = (u32)__builtin_amdgcn_update_dpp(0, (int)v, CTRL, 0xF, 0xF, false);
    return umax32(v, t);
}
// Full wave64 u32 max, broadcast uniformly via readlane (proven in R4/R5).
__device__ __forceinline__ u32 wave_umax(u32 v) {
    v = dpp_max_step<0x111>(v);  // row_shr:1
    v = dpp_max_step<0x112>(v);  // row_shr:2
    v = dpp_max_step<0x114>(v);  // row_shr:4
    v = dpp_max_step<0x118>(v);  // row_shr:8
    v = dpp_max_step<0x142>(v);  // row_bcast:15
    v = dpp_max_step<0x143>(v);  // row_bcast:31
    return (u32)__builtin_amdgcn_readlane((int)v, 63);
}
__device__ __forceinline__ float readlane_f(float v, int l) {
    return __uint_as_float((u32)__builtin_amdgcn_readlane((int)__float_as_uint(v), l));
}
// Distance with XLA's rounding: separate mul/add, no FMA contraction.
__device__ __forceinline__ float dist3(float ax, float ay, float az,
                                       float bx, float by, float bz) {
    const float dx = ax - bx, dy = ay - by, dz = az - bz;
    return __fadd_rn(__fadd_rn(__fmul_rn(dx, dx), __fmul_rn(dy, dy)),
                     __fmul_rn(dz, dz));
}

// ws word layout (u64 granularity):
//   cand  [2][CPOOL]  : 2048 words
//   thrb  [2][NBLK]   :  256 words
//   ready [2][NBLK]   :  256 words
//   fb    [2][NBLK]   :  256 words
//   idx   int32[1024] :  512 words
#define WS_WORDS 3328

__global__ __launch_bounds__(256) void fps_init(u64* ws, int* idx_out) {
    for (int w = threadIdx.x; w < WS_WORDS; w += 256) ws[w] = 0ull;
    if (threadIdx.x == 0) idx_out[0] = 0;   // reference starts at index 0
}

__global__ __launch_bounds__(NTHR) void fps_kernel(const float* __restrict__ coord,
                                                   u64* __restrict__ cand,
                                                   u64* __restrict__ thrb,
                                                   u64* __restrict__ ready,
                                                   u64* __restrict__ fb,
                                                   int* __restrict__ idx_out) {
    const int tid = threadIdx.x;   // 0..63
    const int bid = blockIdx.x;    // 0..127
    const int g   = bid * NTHR + tid;

    // ---- per-thread 13-point state, fully in registers
    float px[PPT], py[PPT], pz[PPT], dmin[PPT];
#pragma unroll
    for (int t = 0; t < PPT; ++t) {
        const bool ok = (t < PPT - 1) || (g < REMTH);
        const int  p  = ok ? (g + t * TOT) : 0;
        px[t] = coord[3 * p]; py[t] = coord[3 * p + 1]; pz[t] = coord[3 * p + 2];
        dmin[t] = 1e10f;  // matches jnp.full((N,), 1e10)
    }

    // selection coord log (per-block LDS; single wave -> __syncthreads is cheap)
    __shared__ float selx[M_SEL], sely[M_SEL], selz[M_SEL];
    if (tid == 0) { selx[0] = coord[0]; sely[0] = coord[1]; selz[0] = coord[2]; }

    // pool state (16 slots/lane, compile-time indexed only)
    float pcx[SPL], pcy[SPL], pcz[SPL], pdm[SPL]; u32 pinv[SPL];
#pragma unroll
    for (int s = 0; s < SPL; ++s) { pcx[s]=0; pcy[s]=0; pcz[s]=0; pdm[s]=0; pinv[s]=0; }

    int nsel = 1, applied = 0, r = 0, ftag = 0;

    for (int guard = 0; guard < 4096 && nsel < M_SEL; ++guard) {
        // ---- catch-up: apply selections [applied, nsel) to the 13-pt state
        __syncthreads();  // selbuf writes (tid0) -> reads (all lanes)
        for (int s = applied; s < nsel; ++s) {
            const float cx = selx[s], cy = sely[s], cz = selz[s];
#pragma unroll
            for (int t = 0; t < PPT; ++t)
                dmin[t] = fminf(dmin[t], dist3(px[t], py[t], pz[t], cx, cy, cz));
        }
        applied = nsel;

        // ---- refill: extract this wave's top-(KPW+1); publish KPW + threshold
        ++r;
        const int par = r & 1;
        u32 rm = 0;  // removal bitmask over the 13 slots
        for (int j = 0; j <= KPW; ++j) {
            u64 lk = 0;
#pragma unroll
            for (int t = 0; t < PPT; ++t) {
                const bool ok = ((t < PPT - 1) || (g < REMTH)) && !((rm >> t) & 1u);
                const u64 k = ((u64)__float_as_uint(dmin[t]) << 17)
                            | (u32)(131071 - (g + t * TOT));
                if (ok && k > lk) lk = k;
            }
            const u32 db = (u32)(lk >> 17);
            const u32 gd = wave_umax(db);
            const u32 iv = (db == gd) ? (u32)(lk & 0x1FFFF) : 0u;
            const u32 gi = wave_umax(iv);
#pragma unroll
            for (int t = 0; t < PPT; ++t) {   // remove the extracted point
                if (__float_as_uint(dmin[t]) == gd &&
                    (u32)(131071 - (g + t * TOT)) == gi) rm |= (1u << t);
            }
            if (tid == 0) {
                const u64 ent = ((u64)gd << 17) | gi;
                if (j < KPW)
                    __hip_atomic_store(&cand[par * CPOOL + bid * KPW + j], ent,
                                       __ATOMIC_RELAXED, __HIP_MEMORY_SCOPE_AGENT);
                else
                    __hip_atomic_store(&thrb[par * NBLK + bid], ent,
                                       __ATOMIC_RELAXED, __HIP_MEMORY_SCOPE_AGENT);
            }
        }
        // publish readiness (release orders the entry stores before it)
        if (tid == 0)
            __hip_atomic_store(&ready[par * NBLK + bid], (u64)r,
                               __ATOMIC_RELEASE, __HIP_MEMORY_SCOPE_AGENT);
        // wait for all 128 waves (parity + monotonic value: ABA-safe)
        {
            u64* ra = &ready[par * NBLK + tid];
            u64* rb = &ready[par * NBLK + tid + 64];
            for (int spin = 0; spin < SPIN_MAX; ++spin) {
                const u64 a = __hip_atomic_load(ra, __ATOMIC_ACQUIRE, __HIP_MEMORY_SCOPE_AGENT);
                const u64 b = __hip_atomic_load(rb, __ATOMIC_ACQUIRE, __HIP_MEMORY_SCOPE_AGENT);
                if (a == (u64)r && b == (u64)r) break;
            }
        }
        // threshold T = max over waves of their 9th-best dmin
        u32 Tbits;
        {
            const u64 ta = __hip_atomic_load(&thrb[par * NBLK + tid],
                                             __ATOMIC_RELAXED, __HIP_MEMORY_SCOPE_AGENT);
            const u64 tb = __hip_atomic_load(&thrb[par * NBLK + tid + 64],
                                             __ATOMIC_RELAXED, __HIP_MEMORY_SCOPE_AGENT);
            Tbits = wave_umax(umax32((u32)(ta >> 17), (u32)(tb >> 17)));
        }
        // load pool: lane l owns entries l, l+64, ..., l+960
#pragma unroll
        for (int s = 0; s < SPL; ++s) {
            const u64 e = __hip_atomic_load(&cand[par * CPOOL + tid + 64 * s],
                                            __ATOMIC_RELAXED, __HIP_MEMORY_SCOPE_AGENT);
            pinv[s] = (u32)(e & 0x1FFFF);
            pdm[s]  = __uint_as_float((u32)(e >> 17));
            int gi2 = 131071 - (int)pinv[s];
            gi2 = gi2 < 0 ? 0 : (gi2 >= N_PTS ? N_PTS - 1 : gi2);   // safety clamp
            pcx[s] = coord[3 * gi2]; pcy[s] = coord[3 * gi2 + 1]; pcz[s] = coord[3 * gi2 + 2];
        }

        // ---- batch: redundant deterministic FPS inside the pool, no comms
        const int batchstart = nsel;
        while (nsel < M_SEL) {
            u64 lk = 0; float bx = 0, by = 0, bz = 0;
#pragma unroll
            for (int s = 0; s < SPL; ++s) {
                const u64 k = ((u64)__float_as_uint(pdm[s]) << 17) | pinv[s];
                const bool w = k > lk;
                lk = w ? k : lk;
                bx = w ? pcx[s] : bx; by = w ? pcy[s] : by; bz = w ? pcz[s] : bz;
            }
            const u32 db = (u32)(lk >> 17);
            const u32 gd = wave_umax(db);
            if (gd <= Tbits) break;   // strict >T required: outside tie could win
            const u32 iv = (db == gd) ? (u32)(lk & 0x1FFFF) : 0u;
            const u32 gi = wave_umax(iv);
            const u64 gk = ((u64)gd << 17) | gi;
            const u64 mk = __ballot(lk == gk);      // exactly one lane (inv unique)
            const int wl = __ffsll((unsigned long long)mk) - 1;
            const float wx = readlane_f(bx, wl), wy = readlane_f(by, wl), wz = readlane_f(bz, wl);
            int gidx = 131071 - (int)gi;
            gidx = gidx < 0 ? 0 : (gidx >= N_PTS ? N_PTS - 1 : gidx);
            if (tid == 0) {
                selx[nsel] = wx; sely[nsel] = wy; selz[nsel] = wz;
                if (bid == 0) idx_out[nsel] = gidx;
            }
            ++nsel;
#pragma unroll
            for (int s = 0; s < SPL; ++s)   // winner's own slot -> dist 0
                pdm[s] = fminf(pdm[s], dist3(pcx[s], pcy[s], pcz[s], wx, wy, wz));
        }
        if (nsel >= M_SEL) break;

        if (nsel == batchstart) {
            // ---- fallback: one exact global argmax step (R4 protocol)
            ++ftag;
            const int fpar = ftag & 1;
            float bd = -1.0f; int bp = 0;
#pragma unroll
            for (int t = 0; t < PPT; ++t) {     // dmin is caught up here
                const bool ok = (t < PPT - 1) || (g < REMTH);
                if (ok && dmin[t] > bd) { bd = dmin[t]; bp = g + t * TOT; }
            }
            const u32 db = __float_as_uint(bd);   // bd >= 0 always
            const u32 gd = wave_umax(db);
            const u32 iv = (db == gd) ? (u32)(131071 - bp) : 0u;
            const u32 gi = wave_umax(iv);
            if (tid == 0) {
                const u64 tg = ((u64)ftag << 49) | ((u64)gd << 17) | gi;
                __hip_atomic_store(&fb[fpar * NBLK + bid], tg,
                                   __ATOMIC_RELAXED, __HIP_MEMORY_SCOPE_AGENT);
            }
            u64 a = 0, b = 0;
            {
                u64* sa = &fb[fpar * NBLK + tid];
                u64* sb = &fb[fpar * NBLK + tid + 64];
                for (int spin = 0; spin < SPIN_MAX; ++spin) {
                    a = __hip_atomic_load(sa, __ATOMIC_RELAXED, __HIP_MEMORY_SCOPE_AGENT);
                    b = __hip_atomic_load(sb, __ATOMIC_RELAXED, __HIP_MEMORY_SCOPE_AGENT);
                    if (((int)(a >> 49) == ftag) & ((int)(b >> 49) == ftag)) break;
                }
            }
            const u64 w   = a > b ? a : b;
            const u32 wd  = (u32)(w >> 17);       // truncation strips the tag
            const u32 fgd = wave_umax(wd);
            const u32 fiv = (wd == fgd) ? (u32)(w & 0x1FFFF) : 0u;
            const u32 fgi = wave_umax(fiv);
            int gidx = 131071 - (int)fgi;
            gidx = gidx < 0 ? 0 : (gidx >= N_PTS ? N_PTS - 1 : gidx);
            if (tid == 0) {
                selx[nsel] = coord[3 * gidx];
                sely[nsel] = coord[3 * gidx + 1];
                selz[nsel] = coord[3 * gidx + 2];
                if (bid == 0) idx_out[nsel] = gidx;
            }
            ++nsel;
        }
    }
}

// out[0 .. 524287]      = feat[idx]  (1024 x 512)
// out[524288 .. 527359] = coord[idx] (1024 x 3)
__global__ __launch_bounds__(128) void gather_kernel(const float* __restrict__ feat,
                                                     const float* __restrict__ coord,
                                                     const int* __restrict__ idx,
                                                     float* __restrict__ out) {
    const int m = blockIdx.x;
    int f = idx[m];
    if (f < 0) f = 0;
    if (f >= N_PTS) f = N_PTS - 1;   // safety clamp
    const int t = threadIdx.x;
    const float4* src = (const float4*)(feat + (size_t)f * 512);
    float4*       dst = (float4*)(out + (size_t)m * 512);
    dst[t] = src[t];  // 128 threads x float4 = 512 floats
    if (t < 3) out[(size_t)M_SEL * 512 + m * 3 + t] = coord[f * 3 + t];
}

extern "C" void kernel_launch(void* const* d_in, const int* in_sizes, int n_in,
                              void* d_out, int out_size, void* d_ws, size_t ws_size,
                              hipStream_t stream) {
    const float* feat  = (const float*)d_in[0];   // (100000, 512) f32
    const float* coord = (const float*)d_in[1];   // (100000, 3)   f32
    float* out = (float*)d_out;

    u64* ws    = (u64*)d_ws;
    u64* cand  = ws;                       // [2][CPOOL]
    u64* thrb  = cand + 2 * CPOOL;         // [2][NBLK]
    u64* ready = thrb + 2 * NBLK;          // [2][NBLK]
    u64* fb    = ready + 2 * NBLK;         // [2][NBLK]
    int* idx   = (int*)(fb + 2 * NBLK);    // int32[1024]

    fps_init<<<1, 256, 0, stream>>>(ws, idx);
    fps_kernel<<<NBLK, NTHR, 0, stream>>>(coord, cand, thrb, ready, fb, idx);
    gather_kernel<<<M_SEL, 128, 0, stream>>>(feat, coord, idx, out);
}